// Round 13
// baseline (568.038 us; speedup 1.0000x reference)
//
#include <hip/hip_runtime.h>

typedef __attribute__((ext_vector_type(8))) short bf16x8;
typedef __attribute__((ext_vector_type(4))) float f32x4;
typedef __attribute__((ext_vector_type(4))) int   i32x4;

#define NROWS     131072
#define KCODES    1024
#define OUT_ELEMS 8388608
#define NBLK      1024              // 128 rows/block; 4 blocks/CU = one resident generation
#define MAGICF    12582912.0f       // 1.5 * 2^23
#define MARGIN    240               // key-quanta (2^-16 t-units); >= 2x worst-case screen err
#define XSTRIDE   65
#define NCAND     10                // candidate slots/row; P(overflow) ~ 1e-7/row
// d_ws layout
#define WS_PART   0                 // 1024 doubles (8 KB)
#define WS_SE     (8*1024)          // 1024 f32 exact ||e||^2
#define WS_SEMG   (12*1024)         // 1024 f32: MAGICF + se*2^16 (MFMA acc-init)
#define WS_BPREP  (16*1024)         // 64 chunks * 2 frags * 64 lanes * 16B = 128 KB

// numpy pairwise sum pattern for n=64 (exact fp32; round-2 verified).
__device__ __forceinline__ float pairwise64_sq(const float* __restrict__ v) {
#pragma clang fp contract(off)
    float r[8];
#pragma unroll
    for (int j = 0; j < 8; ++j) r[j] = v[j] * v[j];
#pragma unroll
    for (int i = 8; i < 64; i += 8) {
#pragma unroll
        for (int j = 0; j < 8; ++j) r[j] += v[i + j] * v[i + j];
    }
    return ((r[0] + r[1]) + (r[2] + r[3])) + ((r[4] + r[5]) + (r[6] + r[7]));
}

__device__ __forceinline__ int med3i(int a, int b, int c) {
    int mn = min(a, b), mx = max(a, b);
    return max(mn, min(mx, c));   // v_med3_i32
}

__device__ __forceinline__ unsigned short rne_bf16(float v) {
    unsigned u = __float_as_uint(v);
    return (unsigned short)((u + 0x7fffu + ((u >> 16) & 1u)) >> 16);
}

__global__ __launch_bounds__(256) void vq_prep(
    const float* __restrict__ emb, float* __restrict__ se,
    float* __restrict__ semg, unsigned short* __restrict__ bprep)
{
#pragma clang fp contract(off)
    const int k = blockIdx.x * 256 + threadIdx.x;
    if (k >= KCODES) return;
    const float* e = emb + (k << 6);
    float s = pairwise64_sq(e);
    se[k]   = s;
    semg[k] = MAGICF + s * 65536.0f;

    const int c = k >> 4, slot = k & 15;
#pragma unroll
    for (int f = 0; f < 2; ++f) {
#pragma unroll
        for (int g = 0; g < 4; ++g) {
            unsigned short h[8];
#pragma unroll
            for (int j = 0; j < 8; ++j)
                h[j] = rne_bf16(e[f * 32 + g * 8 + j] * 256.0f);
            int4 w;
            w.x = h[0] | (h[1] << 16); w.y = h[2] | (h[3] << 16);
            w.z = h[4] | (h[5] << 16); w.w = h[6] | (h[7] << 16);
            *reinterpret_cast<int4*>(bprep + (((c * 2 + f) * 64 + (g * 16 + slot)) << 3)) = w;
        }
    }
}

// Assembled ONLY from sections with observed-healthy codegen:
//   stage/A-build/epilogue = r7 (VGPR 104), sweep = r9 (VGPR 84, unroll-2 ring).
// Post-sweep cross-lane machinery (shfl/ballot, r10-r12, VGPR 52 demotion
// cluster) replaced by plain LDS atomics. (256,2) = r7's regalloc regime;
// NEVER min-waves=4 (r8 spill).
__global__ __launch_bounds__(256, 2) void vq_main(
    const float* __restrict__ lat, const float* __restrict__ emb,
    const float* __restrict__ se_g, const float* __restrict__ semg_g,
    const unsigned short* __restrict__ bprep,
    float* __restrict__ out, double* __restrict__ partials)
{
#pragma clang fp contract(off)
    __shared__ float  x_lds[128 * XSTRIDE];   // 32.5 KB
    __shared__ int    rowmin_lds[128];
    __shared__ int    cnt_lds[128];
    __shared__ int    cand_lds[128][NCAND];   // 5 KB
    __shared__ int    idx_lds[128];
    __shared__ double wsum[4];                // total ~39.0 KB -> 4 blocks/CU

    const int tid = threadIdx.x, l = tid & 63, wv = tid >> 6;
    const int blk = blockIdx.x;
    const int n0 = blk * 128, b = n0 >> 12, hw0 = n0 & 4095;
    const float* latb = lat + ((size_t)b << 18) + hw0;   // elem: latb[(d<<12)+row]

    // ---- init compaction state (before the stage barrier) ----
    if (tid < 128) rowmin_lds[tid] = 0x7fffffff;
    else           cnt_lds[tid - 128] = 0;

    // ---- stage x: float4 along hw (coalesced) ----
    {
        const float4* lat4 = reinterpret_cast<const float4*>(latb);
#pragma unroll
        for (int it = 0; it < 8; ++it) {
            int idx = it * 256 + tid;        // 0..2047
            int d = idx >> 5, hwg = idx & 31;
            float4 v = lat4[(size_t)d * 1024 + hwg];
            int row = hwg * 4;
            x_lds[(row + 0) * XSTRIDE + d] = v.x;
            x_lds[(row + 1) * XSTRIDE + d] = v.y;
            x_lds[(row + 2) * XSTRIDE + d] = v.z;
            x_lds[(row + 3) * XSTRIDE + d] = v.w;
        }
    }
    __syncthreads();

    // ---- A fragments from LDS (r7 form): -2x*2^8 RNE bf16; row=l&15, k=(l>>4)*8+j ----
    bf16x8 afrag[2][2];   // [tile][khalf]
    {
        const int arow = l & 15, kb = (l >> 4) << 3;
#pragma unroll
        for (int T = 0; T < 2; ++T) {
            const float* xr = x_lds + (wv * 32 + T * 16 + arow) * XSTRIDE;
#pragma unroll
            for (int kh = 0; kh < 2; ++kh) {
                bf16x8 f;
#pragma unroll
                for (int j = 0; j < 8; ++j)
                    f[j] = (short)rne_bf16(xr[kh * 32 + kb + j] * -512.0f);
                afrag[T][kh] = f;
            }
        }
    }

    // ---- sweep (r9 verbatim): 64 chunks, acc-init = magic+se*2^16, 4 MFMA/chunk,
    //      key=(bits(acc)<<10)|code, top-3 per (T,reg), 2-buffer unroll-2 ring ----
    int m1[2][4], m2[2][4], m3[2][4];
#pragma unroll
    for (int T = 0; T < 2; ++T)
#pragma unroll
        for (int r = 0; r < 4; ++r) { m1[T][r] = m2[T][r] = m3[T][r] = 0x7fffffff; }

    const i32x4* bp = reinterpret_cast<const i32x4*>(bprep);
    i32x4 bbuf[2][2];
    float sbuf[2];
    bbuf[0][0] = bp[l];
    bbuf[0][1] = bp[64 + l];
    sbuf[0] = semg_g[l & 15];

#pragma unroll 2
    for (int c = 0; c < 64; ++c) {
        const int cur = c & 1, nxt = cur ^ 1;
        if (c < 63) {
            bbuf[nxt][0] = bp[(c + 1) * 128 + l];
            bbuf[nxt][1] = bp[(c + 1) * 128 + 64 + l];
            sbuf[nxt]    = semg_g[(c + 1) * 16 + (l & 15)];
        }
        bf16x8 b0 = __builtin_bit_cast(bf16x8, bbuf[cur][0]);
        bf16x8 b1 = __builtin_bit_cast(bf16x8, bbuf[cur][1]);
        const float sv = sbuf[cur];
        const unsigned code0 = (unsigned)((c << 4) + (l & 15));
#pragma unroll
        for (int T = 0; T < 2; ++T) {
            f32x4 acc = {sv, sv, sv, sv};
            acc = __builtin_amdgcn_mfma_f32_16x16x32_bf16(afrag[T][0], b0, acc, 0, 0, 0);
            acc = __builtin_amdgcn_mfma_f32_16x16x32_bf16(afrag[T][1], b1, acc, 0, 0, 0);
#pragma unroll
            for (int r = 0; r < 4; ++r) {
                // acc in [2^23,2^24): (bits<<10) == t*2^26 + code (mod 2^32),
                // signed-monotone in t for |t*2^16| < 2^21.
                int key = (int)((__float_as_uint(acc[r]) << 10) | code0);
                int n1 = min(key, m1[T][r]);
                int n2 = med3i(key, m1[T][r], m2[T][r]);
                int n3 = med3i(max(key, m1[T][r]), m2[T][r], m3[T][r]);
                m1[T][r] = n1; m2[T][r] = n2; m3[T][r] = n3;
            }
        }
    }

    // ---- row-min via LDS atomics (no shuffles/ballots) ----
    {
        const int g4 = (l >> 4) << 2;
#pragma unroll
        for (int T = 0; T < 2; ++T)
#pragma unroll
            for (int r = 0; r < 4; ++r)
                atomicMin(&rowmin_lds[wv * 32 + T * 16 + g4 + r], m1[T][r]);
    }
    __syncthreads();

    // ---- candidate compaction via LDS atomicAdd ----
    {
        const int g4 = (l >> 4) << 2;
#pragma unroll
        for (int T = 0; T < 2; ++T) {
#pragma unroll
            for (int r = 0; r < 4; ++r) {
                const int row = wv * 32 + T * 16 + g4 + r;
                const int lim = rowmin_lds[row] + (MARGIN << 10) + 1023;
#pragma unroll
                for (int kk = 0; kk < 3; ++kk) {
                    int key = (kk == 0) ? m1[T][r] : (kk == 1) ? m2[T][r] : m3[T][r];
                    if (key <= lim) {
                        int pos = atomicAdd(&cnt_lds[row], 1);
                        if (pos < NCAND) cand_lds[row][pos] = key & 1023;
                    }
                }
            }
        }
    }
    __syncthreads();

    // ---- finalize: one lane per row, exact fp32 re-check (se from L2) ----
    if (tid < 128) {
        const int row = tid;
        const float* xr = x_lds + row * XSTRIDE;
        const float sx = pairwise64_sq(xr);
        const int cnt = cnt_lds[row];
        float bestd = 3.4e38f; int besti = KCODES;
        if (cnt <= NCAND) {
#pragma unroll 1
            for (int i = 0; i < cnt; ++i) {
                int code = cand_lds[row][i];
                const float* e = emb + (code << 6);
                float gacc = 0.0f;
#pragma unroll
                for (int d = 0; d < 64; ++d)
                    gacc = fmaf(xr[d], e[d], gacc);
                float s_   = sx + se_g[code];   // fl32
                float dist = s_ - 2.0f * gacc;  // 2g exact; fl32 subtract
                if (dist < bestd || (dist == bestd && code < besti)) { bestd = dist; besti = code; }
            }
        } else {
            // overflow fallback (P ~ 1e-7 per launch): exact scan, first-index wins
#pragma unroll 1
            for (int code = 0; code < KCODES; ++code) {
                const float* e = emb + (code << 6);
                float gacc = 0.0f;
#pragma unroll
                for (int d = 0; d < 64; ++d)
                    gacc = fmaf(xr[d], e[d], gacc);
                float s_   = sx + se_g[code];
                float dist = s_ - 2.0f * gacc;
                if (dist < bestd) { bestd = dist; besti = code; }
            }
        }
        idx_lds[row] = besti;
        out[OUT_ELEMS + 1 + (size_t)n0 + row] = (float)besti;
    }
    __syncthreads();

    // ---- epilogue (r7 form): q_st coalesced, loss partial ----
    double lsum = 0.0;
    {
        const float aq = 1.0f / 8388608.0f;   // 2^-23 exactly
        const int row = tid & 127, dh = (tid >> 7) * 32;
        const int code = idx_lds[row];
        const float4* eq4 = reinterpret_cast<const float4*>(emb + (code << 6) + dh);
        const float* xr = x_lds + row * XSTRIDE;
        float* ob = out + ((size_t)b << 18) + hw0 + row;
#pragma unroll
        for (int qq = 0; qq < 8; ++qq) {
            float4 qv = eq4[qq];
            float qa[4] = {qv.x, qv.y, qv.z, qv.w};
#pragma unroll
            for (int u = 0; u < 4; ++u) {
                int d = dh + qq * 4 + u;
                float xv = xr[d];
                float qd = qa[u];
                float v  = (xv + aq * qd) + ((1.0f - aq) * qd - xv);
                ob[(size_t)d << 12] = v;
                float diff = qd - xv;
                lsum += (double)diff * (double)diff;
            }
        }
    }

#pragma unroll
    for (int off = 32; off > 0; off >>= 1) lsum += __shfl_down(lsum, off, 64);
    if (l == 0) wsum[wv] = lsum;
    __syncthreads();
    if (tid == 0) partials[blk] = (wsum[0] + wsum[1]) + (wsum[2] + wsum[3]);
}

__global__ __launch_bounds__(512) void vq_finish(
    const double* __restrict__ partials, float* __restrict__ out)
{
    __shared__ double lds[8];
    const int t = threadIdx.x;
    double s = partials[t] + partials[t + 512];
#pragma unroll
    for (int off = 32; off > 0; off >>= 1) s += __shfl_down(s, off, 64);
    if ((t & 63) == 0) lds[t >> 6] = s;
    __syncthreads();
    if (t == 0) {
        double tot = 0.0;
#pragma unroll
        for (int i = 0; i < 8; ++i) tot += lds[i];
        out[OUT_ELEMS] = (float)(0.75 * tot / (double)OUT_ELEMS);
    }
}

extern "C" void kernel_launch(void* const* d_in, const int* in_sizes, int n_in,
                              void* d_out, int out_size, void* d_ws, size_t ws_size,
                              hipStream_t stream)
{
    const float* lat = (const float*)d_in[0];
    const float* emb = (const float*)d_in[1];
    float* out = (float*)d_out;
    char* ws = (char*)d_ws;

    double* partials      = (double*)(ws + WS_PART);
    float* se             = (float*)(ws + WS_SE);
    float* semg           = (float*)(ws + WS_SEMG);
    unsigned short* bprep = (unsigned short*)(ws + WS_BPREP);

    vq_prep<<<dim3(4),    dim3(256), 0, stream>>>(emb, se, semg, bprep);
    vq_main<<<dim3(NBLK), dim3(256), 0, stream>>>(lat, emb, se, semg, bprep, out, partials);
    vq_finish<<<dim3(1),  dim3(512), 0, stream>>>(partials, out);
}

// Round 14
// 97.021 us; speedup vs baseline: 5.8548x; 5.8548x over previous
//
#include <hip/hip_runtime.h>

typedef __attribute__((ext_vector_type(8))) short bf16x8;
typedef __attribute__((ext_vector_type(4))) float f32x4;
typedef __attribute__((ext_vector_type(4))) int   i32x4;

#define NROWS     131072
#define KCODES    1024
#define OUT_ELEMS 8388608
#define RPB       64                // rows per block (r7 halved: LDS 68.6K -> 38.2K)
#define NBLK      2048
#define MAGICF    12582912.0f       // 1.5 * 2^23
#define MARGIN    240               // key-quanta (2^-16 t-units)
#define XSTRIDE   67                // r7's stride
// d_ws layout
#define WS_PART   0                 // 2048 doubles (16 KB)
#define WS_SE     (16*1024)         // 1024 f32 exact ||e||^2
#define WS_SEM    (20*1024)         // 1024 f32: se*2^16 + MAGICF
#define WS_BPREP  (24*1024)         // 64 chunks * 2 frags * 64 lanes * 16B = 128 KB

// numpy pairwise sum pattern for n=64 (exact fp32; round-2 verified).
__device__ __forceinline__ float pairwise64_sq(const float* __restrict__ v) {
#pragma clang fp contract(off)
    float r[8];
#pragma unroll
    for (int j = 0; j < 8; ++j) r[j] = v[j] * v[j];
#pragma unroll
    for (int i = 8; i < 64; i += 8) {
#pragma unroll
        for (int j = 0; j < 8; ++j) r[j] += v[i + j] * v[i + j];
    }
    return ((r[0] + r[1]) + (r[2] + r[3])) + ((r[4] + r[5]) + (r[6] + r[7]));
}

__device__ __forceinline__ int med3i(int a, int b, int c) {
    int mn = min(a, b), mx = max(a, b);
    return max(mn, min(mx, c));   // v_med3_i32
}

__device__ __forceinline__ unsigned short rne_bf16(float v) {
    unsigned u = __float_as_uint(v);
    return (unsigned short)((u + 0x7fffu + ((u >> 16) & 1u)) >> 16);
}

// r7's prep verbatim: exact se; sem = se*2^16 + magic; single-split bf16 B
// frags scaled 2^8 RNE. chunk c=k>>4, frag f=khalf, lane l=g*16+(k&15).
__global__ __launch_bounds__(256) void vq_prep(
    const float* __restrict__ emb, float* __restrict__ se,
    float* __restrict__ sem, unsigned short* __restrict__ bprep)
{
#pragma clang fp contract(off)
    const int k = blockIdx.x * 256 + threadIdx.x;
    if (k >= KCODES) return;
    const float* e = emb + (k << 6);
    float s = pairwise64_sq(e);
    se[k]  = s;
    sem[k] = (s * 65536.0f) + MAGICF;

    const int c = k >> 4, slot = k & 15;
#pragma unroll
    for (int f = 0; f < 2; ++f) {
#pragma unroll
        for (int g = 0; g < 4; ++g) {
            unsigned short h[8];
#pragma unroll
            for (int j = 0; j < 8; ++j)
                h[j] = rne_bf16(e[f * 32 + g * 8 + j] * 256.0f);
            int4 w;
            w.x = h[0] | (h[1] << 16); w.y = h[2] | (h[3] << 16);
            w.z = h[4] | (h[5] << 16); w.w = h[6] | (h[7] << 16);
            *reinterpret_cast<int4*>(bprep + (((c * 2 + f) * 64 + (g * 16 + slot)) << 3)) = w;
        }
    }
}

// r7 structure at 64 rows/block. Everything else verbatim-r7: scalar x stage,
// LDS se/sem tables, acc={0}+sevm key build, 2-buffer unroll-2 ring, keys_lds
// dump, bounded margin-scan finalize (NO compaction, NO fallback -- r11-r13's
// 1024-code fallback cliff was the 5x VALU inflation). (256,2) regalloc regime;
// never min-waves=4 (r8 spill).
__global__ __launch_bounds__(256, 2) void vq_main(
    const float* __restrict__ lat, const float* __restrict__ emb,
    const float* __restrict__ se_g, const float* __restrict__ sem_g,
    const unsigned short* __restrict__ bprep,
    float* __restrict__ out, double* __restrict__ partials)
{
#pragma clang fp contract(off)
    __shared__ float  x_lds[RPB * XSTRIDE];   // 17.2 KB
    __shared__ float  se_lds[KCODES];         // 4 KB
    __shared__ float  sem_lds[KCODES];        // 4 KB
    __shared__ int    keys_lds[RPB * 49];     // 12.5 KB
    __shared__ int    idx_lds[RPB];
    __shared__ double wsum[4];                // total ~38.2 KB -> 4 blocks/CU

    const int tid = threadIdx.x, l = tid & 63, wv = tid >> 6;
    const int blk = blockIdx.x;
    const int n0 = blk * RPB, b = n0 >> 12, hw0 = n0 & 4095;
    const float* latb = lat + ((size_t)b << 18) + hw0;   // elem: latb[(d<<12)+row]

    // ---- stage x (r7 form, scalar, coalesced across rows) + se/sem tables ----
    {
        const int row = tid & 63, dbase = (tid >> 6) * 16;
#pragma unroll
        for (int dd = 0; dd < 16; ++dd) {
            int d = dbase + dd;
            x_lds[row * XSTRIDE + d] = latb[((size_t)d << 12) + row];
        }
    }
    for (int i = tid; i < KCODES; i += 256) { se_lds[i] = se_g[i]; sem_lds[i] = sem_g[i]; }
    __syncthreads();

    // ---- A fragments from LDS: -2x*2^8 RNE bf16; row=l&15, k=(l>>4)*8+j ----
    bf16x8 afrag[2];   // [khalf]; wave wv owns rows wv*16..wv*16+15
    {
        const int arow = l & 15, kb = (l >> 4) << 3;
        const float* xr = x_lds + (wv * 16 + arow) * XSTRIDE;
#pragma unroll
        for (int kh = 0; kh < 2; ++kh) {
            bf16x8 f;
#pragma unroll
            for (int j = 0; j < 8; ++j)
                f[j] = (short)rne_bf16(xr[kh * 32 + kb + j] * -512.0f);
            afrag[kh] = f;
        }
    }

    // ---- sweep (r7 verbatim minus T): 64 chunks, 2 MFMA/chunk, top-3/(reg) ----
    int m1[4], m2[4], m3[4];
#pragma unroll
    for (int r = 0; r < 4; ++r) { m1[r] = m2[r] = m3[r] = 0x7fffffff; }

    const i32x4* bp = reinterpret_cast<const i32x4*>(bprep);
    i32x4 bbuf[2][2];
    bbuf[0][0] = bp[l];
    bbuf[0][1] = bp[64 + l];

#pragma unroll 2
    for (int c = 0; c < 64; ++c) {
        const int cur = c & 1, nxt = cur ^ 1;
        if (c < 63) {
            bbuf[nxt][0] = bp[(c + 1) * 128 + l];
            bbuf[nxt][1] = bp[(c + 1) * 128 + 64 + l];
        }
        const float sevm = sem_lds[c * 16 + (l & 15)];   // se*2^16 + magic
        bf16x8 b0 = __builtin_bit_cast(bf16x8, bbuf[cur][0]);
        bf16x8 b1 = __builtin_bit_cast(bf16x8, bbuf[cur][1]);
        const unsigned code0 = (unsigned)((c << 4) + (l & 15));
        f32x4 acc = {0.f, 0.f, 0.f, 0.f};
        acc = __builtin_amdgcn_mfma_f32_16x16x32_bf16(afrag[0], b0, acc, 0, 0, 0);
        acc = __builtin_amdgcn_mfma_f32_16x16x32_bf16(afrag[1], b1, acc, 0, 0, 0);
#pragma unroll
        for (int r = 0; r < 4; ++r) {
            float uf = acc[r] + sevm;            // t*2^16 + magic, int-grid
            int key = (int)((__float_as_uint(uf) << 10) | code0);   // monotone
            int n1 = min(key, m1[r]);
            int n2 = med3i(key, m1[r], m2[r]);
            int n3 = med3i(max(key, m1[r]), m2[r], m3[r]);
            m1[r] = n1; m2[r] = n2; m3[r] = n3;
        }
    }

    // ---- dump top-3 keys (C map: row=(l>>4)*4+r, col=l&15) ----
#pragma unroll
    for (int r = 0; r < 4; ++r) {
        const int rloc = wv * 16 + ((l >> 4) << 2) + r;
        keys_lds[rloc * 49 + (l & 15) * 3 + 0] = m1[r];
        keys_lds[rloc * 49 + (l & 15) * 3 + 1] = m2[r];
        keys_lds[rloc * 49 + (l & 15) * 3 + 2] = m3[r];
    }
    __syncthreads();

    // ---- finalize: 4 threads/row, 12 keys each; exact fp32 re-check ----
    {
        const int row = tid >> 2, h = tid & 3;
        const int kbase = row * 49 + h * 12;
        int mk = 0x7fffffff;
#pragma unroll
        for (int i = 0; i < 12; ++i) mk = min(mk, keys_lds[kbase + i]);
        mk = min(mk, __shfl_xor(mk, 1, 64));
        mk = min(mk, __shfl_xor(mk, 2, 64));
        const int lim = mk + (MARGIN << 10) + 1023;

        // sx: numpy pairwise; thread h owns accumulators r[2h], r[2h+1]
        const float* xr = x_lds + row * XSTRIDE;
        float rr0 = 0.0f, rr1 = 0.0f;
#pragma unroll
        for (int i = 0; i < 64; i += 8) {
            float v0 = xr[i + 2 * h];
            float v1 = xr[i + 2 * h + 1];
            rr0 += v0 * v0;
            rr1 += v1 * v1;
        }
        float s_h = rr0 + rr1;                       // r[2h]+r[2h+1]
        float p   = s_h + __shfl_xor(s_h, 1, 64);    // (s0+s1) / (s2+s3)
        float sx  = p + __shfl_xor(p, 2, 64);        // numpy combine tree

        float bestd = 3.4e38f; int besti = KCODES;
#pragma unroll 4
        for (int i = 0; i < 12; ++i) {
            int key = keys_lds[kbase + i];
            if (key <= lim) {
                int code = key & 1023;
                const float* e = emb + (code << 6);
                float g = 0.0f;
#pragma unroll
                for (int d = 0; d < 64; ++d)
                    g = fmaf(xr[d], e[d], g);
                float ss   = sx + se_lds[code];  // fl32
                float dist = ss - 2.0f * g;      // 2g exact; fl32 subtract
                if (dist < bestd || (dist == bestd && code < besti)) { bestd = dist; besti = code; }
            }
        }
#pragma unroll
        for (int off = 1; off <= 2; off <<= 1) {
            float od = __shfl_xor(bestd, off, 64);
            int   oi = __shfl_xor(besti, off, 64);
            if (od < bestd || (od == bestd && oi < besti)) { bestd = od; besti = oi; }
        }
        if (h == 0) {
            idx_lds[row] = besti;
            out[OUT_ELEMS + 1 + (size_t)n0 + row] = (float)besti;
        }
    }
    __syncthreads();

    // ---- epilogue (r7 form): q_st coalesced, loss partial ----
    double lsum = 0.0;
    {
        const float aq = 1.0f / 8388608.0f;   // 2^-23 exactly
        const int row = tid & 63, dh = (tid >> 6) * 16;
        const int code = idx_lds[row];
        const float4* eq4 = reinterpret_cast<const float4*>(emb + (code << 6) + dh);
        const float* xr = x_lds + row * XSTRIDE;
        float* ob = out + ((size_t)b << 18) + hw0 + row;
#pragma unroll
        for (int qq = 0; qq < 4; ++qq) {
            float4 qv = eq4[qq];
            float qa[4] = {qv.x, qv.y, qv.z, qv.w};
#pragma unroll
            for (int u = 0; u < 4; ++u) {
                int d = dh + qq * 4 + u;
                float xv = xr[d];
                float qd = qa[u];
                float v  = (xv + aq * qd) + ((1.0f - aq) * qd - xv);
                ob[(size_t)d << 12] = v;
                float diff = qd - xv;
                lsum += (double)diff * (double)diff;
            }
        }
    }

#pragma unroll
    for (int off = 32; off > 0; off >>= 1) lsum += __shfl_down(lsum, off, 64);
    if (l == 0) wsum[wv] = lsum;
    __syncthreads();
    if (tid == 0) partials[blk] = (wsum[0] + wsum[1]) + (wsum[2] + wsum[3]);
}

__global__ __launch_bounds__(512) void vq_finish(
    const double* __restrict__ partials, float* __restrict__ out)
{
    __shared__ double lds[8];
    const int t = threadIdx.x;
    double s = ((partials[t] + partials[t + 512]) + partials[t + 1024]) + partials[t + 1536];
#pragma unroll
    for (int off = 32; off > 0; off >>= 1) s += __shfl_down(s, off, 64);
    if ((t & 63) == 0) lds[t >> 6] = s;
    __syncthreads();
    if (t == 0) {
        double tot = 0.0;
#pragma unroll
        for (int i = 0; i < 8; ++i) tot += lds[i];
        out[OUT_ELEMS] = (float)(0.75 * tot / (double)OUT_ELEMS);
    }
}

extern "C" void kernel_launch(void* const* d_in, const int* in_sizes, int n_in,
                              void* d_out, int out_size, void* d_ws, size_t ws_size,
                              hipStream_t stream)
{
    const float* lat = (const float*)d_in[0];
    const float* emb = (const float*)d_in[1];
    float* out = (float*)d_out;
    char* ws = (char*)d_ws;

    double* partials      = (double*)(ws + WS_PART);
    float* se             = (float*)(ws + WS_SE);
    float* sem            = (float*)(ws + WS_SEM);
    unsigned short* bprep = (unsigned short*)(ws + WS_BPREP);

    vq_prep<<<dim3(4),    dim3(256), 0, stream>>>(emb, se, sem, bprep);
    vq_main<<<dim3(NBLK), dim3(256), 0, stream>>>(lat, emb, se, sem, bprep, out, partials);
    vq_finish<<<dim3(1),  dim3(512), 0, stream>>>(partials, out);
}

// Round 15
// 92.020 us; speedup vs baseline: 6.1730x; 1.0544x over previous
//
#include <hip/hip_runtime.h>

typedef __attribute__((ext_vector_type(8))) short bf16x8;
typedef __attribute__((ext_vector_type(4))) float f32x4;
typedef __attribute__((ext_vector_type(4))) int   i32x4;

#define NROWS     131072
#define KCODES    1024
#define OUT_ELEMS 8388608
#define RPB       64                // rows per block
#define NBLK      2048
#define MAGICF    12582912.0f       // 1.5 * 2^23
#define MARGIN    240               // key-quanta (2^-16 t-units)
#define XSTRIDE   67
// d_ws layout
#define WS_PART   0                 // 2048 doubles (16 KB)
#define WS_SE     (16*1024)         // 1024 f32 exact ||e||^2
#define WS_SEMG   (20*1024)         // 1024 f32: MAGICF + se*2^16 (MFMA acc-init)
#define WS_BPREP  (24*1024)         // 64 chunks * 2 frags * 64 lanes * 16B = 128 KB

// numpy pairwise sum pattern for n=64 (exact fp32; round-2 verified).
__device__ __forceinline__ float pairwise64_sq(const float* __restrict__ v) {
#pragma clang fp contract(off)
    float r[8];
#pragma unroll
    for (int j = 0; j < 8; ++j) r[j] = v[j] * v[j];
#pragma unroll
    for (int i = 8; i < 64; i += 8) {
#pragma unroll
        for (int j = 0; j < 8; ++j) r[j] += v[i + j] * v[i + j];
    }
    return ((r[0] + r[1]) + (r[2] + r[3])) + ((r[4] + r[5]) + (r[6] + r[7]));
}

__device__ __forceinline__ int med3i(int a, int b, int c) {
    int mn = min(a, b), mx = max(a, b);
    return max(mn, min(mx, c));   // v_med3_i32
}

__device__ __forceinline__ unsigned short rne_bf16(float v) {
    unsigned u = __float_as_uint(v);
    return (unsigned short)((u + 0x7fffu + ((u >> 16) & 1u)) >> 16);
}

__global__ __launch_bounds__(256) void vq_prep(
    const float* __restrict__ emb, float* __restrict__ se,
    float* __restrict__ semg, unsigned short* __restrict__ bprep)
{
#pragma clang fp contract(off)
    const int k = blockIdx.x * 256 + threadIdx.x;
    if (k >= KCODES) return;
    const float* e = emb + (k << 6);
    float s = pairwise64_sq(e);
    se[k]   = s;
    semg[k] = MAGICF + s * 65536.0f;

    const int c = k >> 4, slot = k & 15;
#pragma unroll
    for (int f = 0; f < 2; ++f) {
#pragma unroll
        for (int g = 0; g < 4; ++g) {
            unsigned short h[8];
#pragma unroll
            for (int j = 0; j < 8; ++j)
                h[j] = rne_bf16(e[f * 32 + g * 8 + j] * 256.0f);
            int4 w;
            w.x = h[0] | (h[1] << 16); w.y = h[2] | (h[3] << 16);
            w.z = h[4] | (h[5] << 16); w.w = h[6] | (h[7] << 16);
            *reinterpret_cast<int4*>(bprep + (((c * 2 + f) * 64 + (g * 16 + slot)) << 3)) = w;
        }
    }
}

// r14 structure + cooperative LDS staging of the B-stream (global_load_lds,
// double-buffered 4KB pair slots, 1 barrier/pair). Sweep acc-init = r9's
// semg fold (no in-loop LDS table read). keys/finalize/epilogue = r14 verbatim.
// (256,2) regalloc regime; never min-waves=4 (r8 spill).
__global__ __launch_bounds__(256, 2) void vq_main(
    const float* __restrict__ lat, const float* __restrict__ emb,
    const float* __restrict__ se_g, const float* __restrict__ semg_g,
    const unsigned short* __restrict__ bprep,
    float* __restrict__ out, double* __restrict__ partials)
{
#pragma clang fp contract(off)
    __shared__ float  x_lds[RPB * XSTRIDE];   // 17.2 KB
    __shared__ int    keys_lds[RPB * 49];     // 12.5 KB
    __shared__ i32x4  stage4[512];            // 8 KB: 2 slots x 2 chunks x 2KB
    __shared__ int    idx_lds[RPB];
    __shared__ double wsum[4];                // total ~38.3 KB -> 4 blocks/CU

    const int tid = threadIdx.x, l = tid & 63, wv = tid >> 6;
    const int blk = blockIdx.x;
    const int n0 = blk * RPB, b = n0 >> 12, hw0 = n0 & 4095;
    const float* latb = lat + ((size_t)b << 18) + hw0;   // elem: latb[(d<<12)+row]
    const char* bpb = (const char*)bprep;                // byte view of B-frags
    const int scol = l & 15;

    // Stage one 4KB pair (2 chunks) into slot S: each wave DMAs 1KB.
    // global_load_lds: dst = wave-uniform LDS base + lane*16; src is per-lane.
#define STAGE(P, S)                                                              \
    __builtin_amdgcn_global_load_lds(                                            \
        (const __attribute__((address_space(1))) unsigned int*)                  \
            (bpb + ((P) * 4096 + wv * 1024 + l * 16)),                           \
        (__attribute__((address_space(3))) unsigned int*)                        \
            (&stage4[(S) * 256 + wv * 64]), 16, 0, 0)

    // ---- stage x (r14 form) ----
    {
        const int row = tid & 63, dbase = (tid >> 6) * 16;
#pragma unroll
        for (int dd = 0; dd < 16; ++dd) {
            int d = dbase + dd;
            x_lds[row * XSTRIDE + d] = latb[((size_t)d << 12) + row];
        }
    }
    STAGE(0, 0);          // prologue: pair 0 -> slot 0
    __syncthreads();      // covers x_lds AND stage slot 0

    // ---- A fragments from LDS: -2x*2^8 RNE bf16; row=l&15, k=(l>>4)*8+j ----
    bf16x8 afrag0, afrag1;   // khalf 0/1; wave wv owns rows wv*16..+15
    {
        const int arow = l & 15, kb = (l >> 4) << 3;
        const float* xr = x_lds + (wv * 16 + arow) * XSTRIDE;
        bf16x8 f;
#pragma unroll
        for (int j = 0; j < 8; ++j) f[j] = (short)rne_bf16(xr[kb + j]      * -512.0f);
        afrag0 = f;
#pragma unroll
        for (int j = 0; j < 8; ++j) f[j] = (short)rne_bf16(xr[32 + kb + j] * -512.0f);
        afrag1 = f;
    }

    // ---- sweep: 32 pairs, LDS-staged B, acc-init = magic+se*2^16 (r9 core) ----
    int m1[4], m2[4], m3[4];
#pragma unroll
    for (int r = 0; r < 4; ++r) { m1[r] = m2[r] = m3[r] = 0x7fffffff; }

    // semg prefetch, one pair ahead, named scalars
    float svA0 = semg_g[scol],            svB0 = semg_g[16 + scol];       // chunks 0,1
    float svA1 = semg_g[32 + scol],       svB1 = semg_g[48 + scol];       // chunks 2,3

#define CHUNK(S, CI, CC, SV)                                                          \
    {   i32x4 B0 = stage4[(S) * 256 + (CI) * 128 + l];                                \
        i32x4 B1 = stage4[(S) * 256 + (CI) * 128 + 64 + l];                           \
        bf16x8 b0_ = __builtin_bit_cast(bf16x8, B0);                                  \
        bf16x8 b1_ = __builtin_bit_cast(bf16x8, B1);                                  \
        const unsigned code0_ = (unsigned)(((CC) << 4) + scol);                       \
        f32x4 acc = {SV, SV, SV, SV};                                                 \
        acc = __builtin_amdgcn_mfma_f32_16x16x32_bf16(afrag0, b0_, acc, 0, 0, 0);     \
        acc = __builtin_amdgcn_mfma_f32_16x16x32_bf16(afrag1, b1_, acc, 0, 0, 0);     \
        _Pragma("unroll")                                                             \
        for (int r = 0; r < 4; ++r) {                                                 \
            int key = (int)((__float_as_uint(acc[r]) << 10) | code0_);                \
            int n1 = min(key, m1[r]);                                                 \
            int n2 = med3i(key, m1[r], m2[r]);                                        \
            int n3 = med3i(max(key, m1[r]), m2[r], m3[r]);                            \
            m1[r] = n1; m2[r] = n2; m3[r] = n3;                                       \
        }                                                                             \
    }

#pragma unroll 1
    for (int p = 0; p < 32; p += 2) {
        // A: consume pair p (slot 0); stage pair p+1 -> slot 1
        if (p + 1 < 32) STAGE(p + 1, 1);
        CHUNK(0, 0, 2 * p,     svA0);
        CHUNK(0, 1, 2 * p + 1, svB0);
        if (p + 2 < 32) {
            svA0 = semg_g[(2 * p + 4) * 16 + scol];
            svB0 = semg_g[(2 * p + 5) * 16 + scol];
        }
        __syncthreads();   // pair p+1 resident; everyone done reading slot 0

        // B: consume pair p+1 (slot 1); stage pair p+2 -> slot 0
        if (p + 2 < 32) STAGE(p + 2, 0);
        CHUNK(1, 0, 2 * p + 2, svA1);
        CHUNK(1, 1, 2 * p + 3, svB1);
        if (p + 3 < 32) {
            svA1 = semg_g[(2 * p + 6) * 16 + scol];
            svB1 = semg_g[(2 * p + 7) * 16 + scol];
        }
        __syncthreads();   // pair p+2 resident; everyone done reading slot 1
    }
#undef CHUNK
#undef STAGE

    // ---- dump top-3 keys (C map: row=(l>>4)*4+r, col=l&15) ----
#pragma unroll
    for (int r = 0; r < 4; ++r) {
        const int rloc = wv * 16 + ((l >> 4) << 2) + r;
        keys_lds[rloc * 49 + (l & 15) * 3 + 0] = m1[r];
        keys_lds[rloc * 49 + (l & 15) * 3 + 1] = m2[r];
        keys_lds[rloc * 49 + (l & 15) * 3 + 2] = m3[r];
    }
    __syncthreads();

    // ---- finalize (r14 form): 4 threads/row, 12 keys each; exact fp32 re-check ----
    {
        const int row = tid >> 2, h = tid & 3;
        const int kbase = row * 49 + h * 12;
        int mk = 0x7fffffff;
#pragma unroll
        for (int i = 0; i < 12; ++i) mk = min(mk, keys_lds[kbase + i]);
        mk = min(mk, __shfl_xor(mk, 1, 64));
        mk = min(mk, __shfl_xor(mk, 2, 64));
        const int lim = mk + (MARGIN << 10) + 1023;

        // sx: numpy pairwise; thread h owns accumulators r[2h], r[2h+1]
        const float* xr = x_lds + row * XSTRIDE;
        float rr0 = 0.0f, rr1 = 0.0f;
#pragma unroll
        for (int i = 0; i < 64; i += 8) {
            float v0 = xr[i + 2 * h];
            float v1 = xr[i + 2 * h + 1];
            rr0 += v0 * v0;
            rr1 += v1 * v1;
        }
        float s_h = rr0 + rr1;                       // r[2h]+r[2h+1]
        float pq  = s_h + __shfl_xor(s_h, 1, 64);    // (s0+s1) / (s2+s3)
        float sx  = pq + __shfl_xor(pq, 2, 64);      // numpy combine tree

        float bestd = 3.4e38f; int besti = KCODES;
#pragma unroll 4
        for (int i = 0; i < 12; ++i) {
            int key = keys_lds[kbase + i];
            if (key <= lim) {
                int code = key & 1023;
                const float* e = emb + (code << 6);
                float g = 0.0f;
#pragma unroll
                for (int d = 0; d < 64; ++d)
                    g = fmaf(xr[d], e[d], g);
                float ss   = sx + se_g[code];    // fl32
                float dist = ss - 2.0f * g;      // 2g exact; fl32 subtract
                if (dist < bestd || (dist == bestd && code < besti)) { bestd = dist; besti = code; }
            }
        }
#pragma unroll
        for (int off = 1; off <= 2; off <<= 1) {
            float od = __shfl_xor(bestd, off, 64);
            int   oi = __shfl_xor(besti, off, 64);
            if (od < bestd || (od == bestd && oi < besti)) { bestd = od; besti = oi; }
        }
        if (h == 0) {
            idx_lds[row] = besti;
            out[OUT_ELEMS + 1 + (size_t)n0 + row] = (float)besti;
        }
    }
    __syncthreads();

    // ---- epilogue (r14 form): q_st coalesced, loss partial ----
    double lsum = 0.0;
    {
        const float aq = 1.0f / 8388608.0f;   // 2^-23 exactly
        const int row = tid & 63, dh = (tid >> 6) * 16;
        const int code = idx_lds[row];
        const float4* eq4 = reinterpret_cast<const float4*>(emb + (code << 6) + dh);
        const float* xr = x_lds + row * XSTRIDE;
        float* ob = out + ((size_t)b << 18) + hw0 + row;
#pragma unroll
        for (int qq = 0; qq < 4; ++qq) {
            float4 qv = eq4[qq];
            float qa[4] = {qv.x, qv.y, qv.z, qv.w};
#pragma unroll
            for (int u = 0; u < 4; ++u) {
                int d = dh + qq * 4 + u;
                float xv = xr[d];
                float qd = qa[u];
                float v  = (xv + aq * qd) + ((1.0f - aq) * qd - xv);
                ob[(size_t)d << 12] = v;
                float diff = qd - xv;
                lsum += (double)diff * (double)diff;
            }
        }
    }

#pragma unroll
    for (int off = 32; off > 0; off >>= 1) lsum += __shfl_down(lsum, off, 64);
    if (l == 0) wsum[wv] = lsum;
    __syncthreads();
    if (tid == 0) partials[blk] = (wsum[0] + wsum[1]) + (wsum[2] + wsum[3]);
}

__global__ __launch_bounds__(512) void vq_finish(
    const double* __restrict__ partials, float* __restrict__ out)
{
    __shared__ double lds[8];
    const int t = threadIdx.x;
    double s = ((partials[t] + partials[t + 512]) + partials[t + 1024]) + partials[t + 1536];
#pragma unroll
    for (int off = 32; off > 0; off >>= 1) s += __shfl_down(s, off, 64);
    if ((t & 63) == 0) lds[t >> 6] = s;
    __syncthreads();
    if (t == 0) {
        double tot = 0.0;
#pragma unroll
        for (int i = 0; i < 8; ++i) tot += lds[i];
        out[OUT_ELEMS] = (float)(0.75 * tot / (double)OUT_ELEMS);
    }
}

extern "C" void kernel_launch(void* const* d_in, const int* in_sizes, int n_in,
                              void* d_out, int out_size, void* d_ws, size_t ws_size,
                              hipStream_t stream)
{
    const float* lat = (const float*)d_in[0];
    const float* emb = (const float*)d_in[1];
    float* out = (float*)d_out;
    char* ws = (char*)d_ws;

    double* partials      = (double*)(ws + WS_PART);
    float* se             = (float*)(ws + WS_SE);
    float* semg           = (float*)(ws + WS_SEMG);
    unsigned short* bprep = (unsigned short*)(ws + WS_BPREP);

    vq_prep<<<dim3(4),    dim3(256), 0, stream>>>(emb, se, semg, bprep);
    vq_main<<<dim3(NBLK), dim3(256), 0, stream>>>(lat, emb, se, semg, bprep, out, partials);
    vq_finish<<<dim3(1),  dim3(512), 0, stream>>>(partials, out);
}